// Round 7
// baseline (440.485 us; speedup 1.0000x reference)
//
#include <hip/hip_runtime.h>
#include <hip/hip_bf16.h>

// Problem constants (fixed by setup_inputs)
#define N0_ 3514368
#define T0_ 135168
#define T1_ 12288
#define F0_ 25
#define F1_ 10
#define D_  100
#define H_  256
#define C_  128
#define IC_ 4096
// T0 = 132 * 1024 exactly
#define CBLK_ 132

// Fragment geometry (16x16x32 bf16 MFMA), HW-verified in R2-R6:
//   A: lane holds A[row = 16*rb + (lane&15)][k = ks*32 + (lane>>4)*8 + j]
//   B: lane holds W[k][n = 16*nb + (lane&15)], same k mapping
//   C: col = lane&15, row = (lane>>4)*4 + q
// K = 256: ks 0..3 = neigh feats (0..99 zero-padded), ks 4..7 = self feats.

typedef __attribute__((ext_vector_type(8))) short bf8_t;
typedef __attribute__((ext_vector_type(4))) float f4_t;

__device__ inline void split_bf16(float v, ushort& hi, ushort& lo) {
    __hip_bfloat16 hb = __float2bfloat16(v);
    float hf = __bfloat162float(hb);
    __hip_bfloat16 lb = __float2bfloat16(v - hf);
    hi = *reinterpret_cast<ushort*>(&hb);
    lo = *reinterpret_cast<ushort*>(&lb);
}

__device__ inline float bf2f(ushort u) {
    unsigned int w = ((unsigned int)u) << 16;
    return *reinterpret_cast<float*>(&w);
}

// ---------------------------------------------------------------------------
// Bz: zero the needed-row flags (T0 bytes).
// ---------------------------------------------------------------------------
__global__ __launch_bounds__(256) void bz_zero(unsigned int* __restrict__ flag32) {
    const int i = blockIdx.x * 256 + threadIdx.x;
    if (i < T0_ / 4) flag32[i] = 0u;
}

// ---------------------------------------------------------------------------
// Bs: set flags for rows referenced by layer 1: unique(col1) U [0,T1).
// ---------------------------------------------------------------------------
__global__ __launch_bounds__(256) void bs_set(const int* __restrict__ col1,
                                              unsigned char* __restrict__ flag) {
    const int i = blockIdx.x * 256 + threadIdx.x;
    if (i < T1_ * F1_) flag[col1[i]] = 1;
    if (i < T1_) flag[i] = 1;
}

// ---------------------------------------------------------------------------
// Kc: single-block ordered compaction (count+scan+emit fused, deterministic).
// 1024 threads sweep 132 chunks of 1024 rows with a running offset.
// ---------------------------------------------------------------------------
__global__ __launch_bounds__(1024) void kc_all(const unsigned char* __restrict__ flag,
                                               int* __restrict__ rowlist,
                                               int* __restrict__ ntot) {
    __shared__ int wsum[16];
    __shared__ int woff[16];
    __shared__ int base;
    if (threadIdx.x == 0) base = 0;
    __syncthreads();
    const int lane = threadIdx.x & 63, w = threadIdx.x >> 6;
    for (int c = 0; c < CBLK_; ++c) {
        const int i = c * 1024 + threadIdx.x;
        const int pred = flag[i] ? 1 : 0;
        unsigned long long b = __ballot(pred);
        const int lanepre = __popcll(b & ((1ULL << lane) - 1ULL));
        if (lane == 0) wsum[w] = __popcll(b);
        __syncthreads();
        if (threadIdx.x == 0) {
            int s = base;
            for (int k = 0; k < 16; ++k) { woff[k] = s; s += wsum[k]; }
            base = s;
        }
        __syncthreads();
        if (pred) rowlist[woff[w] + lanepre] = i;
    }
    if (threadIdx.x == 0) ntot[0] = base;
}

// ---------------------------------------------------------------------------
// K0: pack Wn0|Ws0 (each 100x256 f32 [k][n]) into split-bf16 B fragments.
// ---------------------------------------------------------------------------
__global__ __launch_bounds__(256) void k0_packW(const float* __restrict__ Wn0,
                                                const float* __restrict__ Ws0,
                                                ushort* __restrict__ Wpk) {
    const int nb = blockIdx.x;           // 0..15
    for (int it = 0; it < 4; ++it) {
        const int task = threadIdx.x + it * 256;   // ks(8) x part(2) x lane(64)
        const int ks   = task >> 7;
        const int part = (task >> 6) & 1;
        const int lane = task & 63;
        const int n  = nb * 16 + (lane & 15);
        const int kb = (ks & 3) * 32 + (lane >> 4) * 8;
        const float* src = (ks < 4) ? Wn0 : Ws0;
        ushort out[8];
#pragma unroll
        for (int j = 0; j < 8; ++j) {
            const int k = kb + j;
            float v = (k < D_) ? src[k * H_ + n] : 0.f;
            ushort hi, lo;
            split_bf16(v, hi, lo);
            out[j] = part ? lo : hi;
        }
        ushort* dst = Wpk + ((size_t)((nb * 8 + ks) * 2 + part) * 64 + lane) * 8;
        *reinterpret_cast<bf8_t*>(dst) = *reinterpret_cast<bf8_t*>(out);
    }
}

// ---------------------------------------------------------------------------
// K12: fused gather-mean + pack + split-bf16 MFMA + bias + relu over the
// COMPACTED needed-row list. Shared 64KB LDS A-tile, nb-partitioned B across
// 4 waves; h (bf16) stores scatter to original rows.
// ---------------------------------------------------------------------------
__global__ __launch_bounds__(256) void k12_fused(const float* __restrict__ xf,
                                                 const int* __restrict__ col0,
                                                 const ushort* __restrict__ Wpk,
                                                 const float* __restrict__ b0,
                                                 const int* __restrict__ rowlist,
                                                 const int* __restrict__ ntot,
                                                 ushort* __restrict__ hb) {
    __shared__ ushort Afr[4][8][2][512];   // [rb][ks][part][lane*8+j] = 64 KB
    __shared__ int rl[64];
    const int n = ntot[0];
    if (blockIdx.x * 64 >= n) return;      // uniform early-exit, before barriers

    const int lane = threadIdx.x & 63;
    const int wid  = threadIdx.x >> 6;
    const int r    = lane & 15;
    const int kg   = lane >> 4;
    const int cidx = blockIdx.x * 64 + wid * 16 + r;   // compact index
    const bool act = (cidx < n);
    const int orow = rowlist[act ? cidx : 0];

    if (threadIdx.x < 64) {
        const int c2 = blockIdx.x * 64 + threadIdx.x;
        rl[threadIdx.x] = (c2 < n) ? rowlist[c2] : -1;
    }

    // ---- gather phase ----
    float accN[4][8];
    float accS[4][8];
#pragma unroll
    for (int ks = 0; ks < 4; ++ks)
#pragma unroll
        for (int j = 0; j < 8; ++j) { accN[ks][j] = 0.f; accS[ks][j] = 0.f; }

    if (act) {
        const int* cp = col0 + (size_t)orow * F0_;
        int idxs[F0_];
#pragma unroll
        for (int j = 0; j < F0_; ++j) idxs[j] = cp[j];   // break idx->row dep chain
#pragma unroll 5
        for (int jn = 0; jn < F0_; ++jn) {
            const float* rp = xf + (size_t)idxs[jn] * D_;
#pragma unroll
            for (int ks = 0; ks < 3; ++ks) {
                float4 a = *reinterpret_cast<const float4*>(rp + ks * 32 + kg * 8);
                float4 b = *reinterpret_cast<const float4*>(rp + ks * 32 + kg * 8 + 4);
                accN[ks][0] += a.x; accN[ks][1] += a.y; accN[ks][2] += a.z; accN[ks][3] += a.w;
                accN[ks][4] += b.x; accN[ks][5] += b.y; accN[ks][6] += b.z; accN[ks][7] += b.w;
            }
            if (kg == 0) {
                float4 a = *reinterpret_cast<const float4*>(rp + 96);
                accN[3][0] += a.x; accN[3][1] += a.y; accN[3][2] += a.z; accN[3][3] += a.w;
            }
        }
        const float* rp = xf + (size_t)orow * D_;
#pragma unroll
        for (int ks = 0; ks < 3; ++ks) {
            float4 a = *reinterpret_cast<const float4*>(rp + ks * 32 + kg * 8);
            float4 b = *reinterpret_cast<const float4*>(rp + ks * 32 + kg * 8 + 4);
            accS[ks][0] = a.x; accS[ks][1] = a.y; accS[ks][2] = a.z; accS[ks][3] = a.w;
            accS[ks][4] = b.x; accS[ks][5] = b.y; accS[ks][6] = b.z; accS[ks][7] = b.w;
        }
        if (kg == 0) {
            float4 a = *reinterpret_cast<const float4*>(rp + 96);
            accS[3][0] = a.x; accS[3][1] = a.y; accS[3][2] = a.z; accS[3][3] = a.w;
        }
    }

    // ---- pack phase: split-bf16 -> LDS fragments ----
    const float inv = 1.0f / F0_;
#pragma unroll
    for (int ks = 0; ks < 4; ++ks) {
        bf8_t hN, lN, hS, lS;
#pragma unroll
        for (int j = 0; j < 8; ++j) {
            ushort hi, lo;
            split_bf16(accN[ks][j] * inv, hi, lo);
            hN[j] = (short)hi; lN[j] = (short)lo;
            split_bf16(accS[ks][j], hi, lo);
            hS[j] = (short)hi; lS[j] = (short)lo;
        }
        *reinterpret_cast<bf8_t*>(&Afr[wid][ks    ][0][lane * 8]) = hN;
        *reinterpret_cast<bf8_t*>(&Afr[wid][ks    ][1][lane * 8]) = lN;
        *reinterpret_cast<bf8_t*>(&Afr[wid][ks + 4][0][lane * 8]) = hS;
        *reinterpret_cast<bf8_t*>(&Afr[wid][ks + 4][1][lane * 8]) = lS;
    }
    __syncthreads();

    // ---- MFMA phase: wave w -> cols [w*64, w*64+64) for all 64 block rows ----
    const int nb0 = wid * 4;
    f4_t acc[4][4] = {};
#pragma unroll
    for (int ks = 0; ks < 8; ++ks) {
        bf8_t ah[4], al[4], bh[4], bl[4];
#pragma unroll
        for (int rb = 0; rb < 4; ++rb) {
            ah[rb] = *reinterpret_cast<const bf8_t*>(&Afr[rb][ks][0][lane * 8]);
            al[rb] = *reinterpret_cast<const bf8_t*>(&Afr[rb][ks][1][lane * 8]);
        }
#pragma unroll
        for (int ci = 0; ci < 4; ++ci) {
            const ushort* p = Wpk + ((size_t)(((nb0 + ci) * 8 + ks) * 2) * 64 + lane) * 8;
            bh[ci] = *reinterpret_cast<const bf8_t*>(p);
            bl[ci] = *reinterpret_cast<const bf8_t*>(p + 512);
        }
#pragma unroll
        for (int rb = 0; rb < 4; ++rb)
#pragma unroll
            for (int ci = 0; ci < 4; ++ci) {
                acc[rb][ci] = __builtin_amdgcn_mfma_f32_16x16x32_bf16(ah[rb], bh[ci], acc[rb][ci], 0, 0, 0);
                acc[rb][ci] = __builtin_amdgcn_mfma_f32_16x16x32_bf16(ah[rb], bl[ci], acc[rb][ci], 0, 0, 0);
                acc[rb][ci] = __builtin_amdgcn_mfma_f32_16x16x32_bf16(al[rb], bh[ci], acc[rb][ci], 0, 0, 0);
            }
    }

    // ---- epilogue: bias + relu + bf16 scatter-store to original rows ----
    const int col_in = lane & 15;
    const int rgrp   = lane >> 4;
    int orows[4][4];
#pragma unroll
    for (int rb = 0; rb < 4; ++rb)
#pragma unroll
        for (int q = 0; q < 4; ++q)
            orows[rb][q] = rl[rb * 16 + rgrp * 4 + q];
#pragma unroll
    for (int ci = 0; ci < 4; ++ci) {
        const int nn = (nb0 + ci) * 16 + col_in;
        const float bias = b0[nn];
#pragma unroll
        for (int rb = 0; rb < 4; ++rb) {
#pragma unroll
            for (int q = 0; q < 4; ++q) {
                const int o = orows[rb][q];
                if (o >= 0) {
                    float v = acc[rb][ci][q] + bias;
                    v = v > 0.f ? v : 0.f;
                    __hip_bfloat16 bv = __float2bfloat16(v);
                    hb[(size_t)o * H_ + nn] = *reinterpret_cast<ushort*>(&bv);
                }
            }
        }
    }
}

// ---------------------------------------------------------------------------
// K3: out_u = (mean_j h[col1]) @ Wn1 + h[:T1] @ Ws1 + b1   (T1 x 128)
// h is bf16; accumulate f32.
// ---------------------------------------------------------------------------
__global__ __launch_bounds__(256) void k3_layer1(const ushort* __restrict__ hb,
                                                 const int* __restrict__ col1,
                                                 const float* __restrict__ Wn1,
                                                 const float* __restrict__ Ws1,
                                                 const float* __restrict__ b1,
                                                 float* __restrict__ out_u) {
    __shared__ __align__(16) float Ng[16 * H_];
    __shared__ __align__(16) float Sf[16 * H_];
    const int t = threadIdx.x;
    const int base = blockIdx.x * 16;

    for (int r = 0; r < 16; ++r) {
        float a = 0.f;
#pragma unroll
        for (int j = 0; j < F1_; ++j) {
            int idx = col1[(base + r) * F1_ + j];
            a += bf2f(hb[(size_t)idx * H_ + t]);
        }
        Ng[r * H_ + t] = a * (1.0f / F1_);
        Sf[r * H_ + t] = bf2f(hb[(size_t)(base + r) * H_ + t]);
    }
    __syncthreads();

    const int c  = t & (C_ - 1);
    const int rg = t >> 7;
    float acc[8];
    const float bias = b1[c];
#pragma unroll
    for (int r8 = 0; r8 < 8; ++r8) acc[r8] = bias;

    for (int d4 = 0; d4 < H_ / 4; ++d4) {
        const int d = d4 * 4;
        const float wn0_ = Wn1[(d + 0) * C_ + c];
        const float wn1_ = Wn1[(d + 1) * C_ + c];
        const float wn2_ = Wn1[(d + 2) * C_ + c];
        const float wn3_ = Wn1[(d + 3) * C_ + c];
        const float ws0_ = Ws1[(d + 0) * C_ + c];
        const float ws1_ = Ws1[(d + 1) * C_ + c];
        const float ws2_ = Ws1[(d + 2) * C_ + c];
        const float ws3_ = Ws1[(d + 3) * C_ + c];
#pragma unroll
        for (int r8 = 0; r8 < 8; ++r8) {
            const int r = rg * 8 + r8;
            float4 n = *reinterpret_cast<const float4*>(&Ng[r * H_ + d]);
            float4 s = *reinterpret_cast<const float4*>(&Sf[r * H_ + d]);
            acc[r8] += n.x * wn0_ + n.y * wn1_ + n.z * wn2_ + n.w * wn3_
                     + s.x * ws0_ + s.y * ws1_ + s.z * ws2_ + s.w * ws3_;
        }
    }
#pragma unroll
    for (int r8 = 0; r8 < 8; ++r8)
        out_u[(size_t)(base + rg * 8 + r8) * C_ + c] = acc[r8];
}

// ---------------------------------------------------------------------------
// K4: edge scores (8192 edges)
// ---------------------------------------------------------------------------
__global__ __launch_bounds__(256) void k4_edges(const float* __restrict__ out_u,
                                                const int* __restrict__ rmap,
                                                const float* __restrict__ Wp1,
                                                const float* __restrict__ bp1,
                                                const float* __restrict__ Wp2,
                                                const float* __restrict__ bp2,
                                                float* __restrict__ scores) {
    __shared__ __align__(16) float E[32 * C_];
    const int t = threadIdx.x;
    const int base = blockIdx.x * 32;
    const int f = t & 127;
    const int half = t >> 7;

    for (int rr = 0; rr < 16; ++rr) {
        const int row = rr * 2 + half;
        const int j = base + row;
        const int si = rmap[j & (IC_ - 1)];
        const int di = rmap[IC_ + j];
        E[row * C_ + f] = out_u[(size_t)si * C_ + f] * out_u[(size_t)di * C_ + f];
    }
    __syncthreads();

    float acc[16];
    const float bias = bp1[f];
#pragma unroll
    for (int r16 = 0; r16 < 16; ++r16) acc[r16] = bias;

    for (int d4 = 0; d4 < C_ / 4; ++d4) {
        const int d = d4 * 4;
        const float w0 = Wp1[(d + 0) * C_ + f];
        const float w1 = Wp1[(d + 1) * C_ + f];
        const float w2 = Wp1[(d + 2) * C_ + f];
        const float w3 = Wp1[(d + 3) * C_ + f];
#pragma unroll
        for (int r16 = 0; r16 < 16; ++r16) {
            const int r = half * 16 + r16;
            float4 e4 = *reinterpret_cast<const float4*>(&E[r * C_ + d]);
            acc[r16] += e4.x * w0 + e4.y * w1 + e4.z * w2 + e4.w * w3;
        }
    }
    __syncthreads();
#pragma unroll
    for (int r16 = 0; r16 < 16; ++r16) {
        float v = acc[r16];
        E[(half * 16 + r16) * C_ + f] = v > 0.f ? v : 0.f;
    }
    __syncthreads();

    const int r = t >> 3;
    const int s = t & 7;
    float p = 0.f;
#pragma unroll
    for (int k4 = 0; k4 < 4; ++k4) {
        float4 tv = *reinterpret_cast<const float4*>(&E[r * C_ + s * 16 + k4 * 4]);
        float4 wv = *reinterpret_cast<const float4*>(&Wp2[s * 16 + k4 * 4]);
        p += tv.x * wv.x + tv.y * wv.y + tv.z * wv.z + tv.w * wv.w;
    }
    p += __shfl_down(p, 4, 8);
    p += __shfl_down(p, 2, 8);
    p += __shfl_down(p, 1, 8);
    if (s == 0) scores[base + r] = p + bp2[0];
}

// ---------------------------------------------------------------------------
extern "C" void kernel_launch(void* const* d_in, const int* in_sizes, int n_in,
                              void* d_out, int out_size, void* d_ws, size_t ws_size,
                              hipStream_t stream) {
    const float* xf   = (const float*)d_in[0];
    const float* Wn0  = (const float*)d_in[1];
    const float* Ws0  = (const float*)d_in[2];
    const float* b0   = (const float*)d_in[3];
    const float* Wn1  = (const float*)d_in[4];
    const float* Ws1  = (const float*)d_in[5];
    const float* b1   = (const float*)d_in[6];
    const float* Wp1  = (const float*)d_in[7];
    const float* bp1  = (const float*)d_in[8];
    const float* Wp2  = (const float*)d_in[9];
    const float* bp2  = (const float*)d_in[10];
    const int*   col0 = (const int*)d_in[11];
    const int*   col1 = (const int*)d_in[12];
    const int*   rmap = (const int*)d_in[13];

    // workspace layout
    char* ws = (char*)d_ws;
    ushort* hb    = (ushort*)ws;                                // T0*256 bf16 = 69.2 MB
    float*  out_u = (float*)(ws + (size_t)T0_ * H_ * 2);        // T1*128 f32 = 6.3 MB
    ushort* Wpk   = (ushort*)(out_u + (size_t)T1_ * C_);        // 512 KB
    unsigned char* flag = (unsigned char*)(Wpk + (size_t)16 * 8 * 2 * 64 * 8); // T0 B
    int*    ntot    = (int*)(flag + T0_);                       // 1
    int*    rowlist = ntot + 1;                                 // T0
    float*  scores  = (float*)d_out;

    hipLaunchKernelGGL(bz_zero, dim3((T0_ / 4 + 255) / 256), dim3(256), 0, stream,
                       (unsigned int*)flag);
    hipLaunchKernelGGL(bs_set, dim3((T1_ * F1_ + 255) / 256), dim3(256), 0, stream,
                       col1, flag);
    hipLaunchKernelGGL(kc_all, dim3(1), dim3(1024), 0, stream, flag, rowlist, ntot);
    hipLaunchKernelGGL(k0_packW, dim3(16), dim3(256), 0, stream, Wn0, Ws0, Wpk);
    hipLaunchKernelGGL(k12_fused, dim3(T0_ / 64), dim3(256), 0, stream,
                       xf, col0, Wpk, b0, rowlist, ntot, hb);
    hipLaunchKernelGGL(k3_layer1, dim3(T1_ / 16), dim3(256), 0, stream,
                       hb, col1, Wn1, Ws1, b1, out_u);
    hipLaunchKernelGGL(k4_edges, dim3((2 * IC_) / 32), dim3(256), 0, stream,
                       out_u, rmap, Wp1, bp1, Wp2, bp2, scores);
}

// Round 8
// 376.712 us; speedup vs baseline: 1.1693x; 1.1693x over previous
//
#include <hip/hip_runtime.h>
#include <hip/hip_bf16.h>

// Problem constants (fixed by setup_inputs)
#define N0_ 3514368
#define T0_ 135168
#define T1_ 12288
#define F0_ 25
#define F1_ 10
#define D_  100
#define H_  256
#define C_  128
#define IC_ 4096
// T0 = 132 * 1024 exactly
#define CBLK_ 132

// Fragment geometry (16x16x32 bf16 MFMA), HW-verified in R2-R7:
//   A: lane holds A[row = 16*rb + (lane&15)][k = ks*32 + (lane>>4)*8 + j]
//   B: lane holds W[k][n = 16*nb + (lane&15)], same k mapping
//   C: col = lane&15, row = (lane>>4)*4 + q
// K = 256: ks 0..3 = neigh feats (0..99 zero-padded), ks 4..7 = self feats.

typedef __attribute__((ext_vector_type(8))) short bf8_t;
typedef __attribute__((ext_vector_type(4))) float f4_t;

__device__ inline void split_bf16(float v, ushort& hi, ushort& lo) {
    __hip_bfloat16 hb = __float2bfloat16(v);
    float hf = __bfloat162float(hb);
    __hip_bfloat16 lb = __float2bfloat16(v - hf);
    hi = *reinterpret_cast<ushort*>(&hb);
    lo = *reinterpret_cast<ushort*>(&lb);
}

__device__ inline float bf2f(ushort u) {
    unsigned int w = ((unsigned int)u) << 16;
    return *reinterpret_cast<float*>(&w);
}

// ---------------------------------------------------------------------------
// Bz: zero the needed-row flags (T0 bytes).
// ---------------------------------------------------------------------------
__global__ __launch_bounds__(256) void bz_zero(unsigned int* __restrict__ flag32) {
    const int i = blockIdx.x * 256 + threadIdx.x;
    if (i < T0_ / 4) flag32[i] = 0u;
}

// ---------------------------------------------------------------------------
// Bs: set flags for rows referenced by layer 1: unique(col1) U [0,T1).
// ---------------------------------------------------------------------------
__global__ __launch_bounds__(256) void bs_set(const int* __restrict__ col1,
                                              unsigned char* __restrict__ flag) {
    const int i = blockIdx.x * 256 + threadIdx.x;
    if (i < T1_ * F1_) flag[col1[i]] = 1;
    if (i < T1_) flag[i] = 1;
}

// ---------------------------------------------------------------------------
// KcA: per-block (1024 rows) flag counts. PARALLEL (132 blocks).
// ---------------------------------------------------------------------------
__global__ __launch_bounds__(1024) void kc_count(const unsigned char* __restrict__ flag,
                                                 int* __restrict__ counts) {
    __shared__ int wsum[16];
    const int i = blockIdx.x * 1024 + threadIdx.x;
    const int pred = flag[i] ? 1 : 0;
    unsigned long long b = __ballot(pred);
    const int lane = threadIdx.x & 63, w = threadIdx.x >> 6;
    if (lane == 0) wsum[w] = __popcll(b);
    __syncthreads();
    if (threadIdx.x == 0) {
        int s = 0;
        for (int k = 0; k < 16; ++k) s += wsum[k];
        counts[blockIdx.x] = s;
    }
}

// ---------------------------------------------------------------------------
// KcB: serial exclusive scan of the 132 counts (tiny, deterministic).
// ---------------------------------------------------------------------------
__global__ void kc_scan(const int* __restrict__ counts,
                        int* __restrict__ offs, int* __restrict__ ntot) {
    if (threadIdx.x == 0 && blockIdx.x == 0) {
        int s = 0;
        for (int k = 0; k < CBLK_; ++k) { offs[k] = s; s += counts[k]; }
        ntot[0] = s;
    }
}

// ---------------------------------------------------------------------------
// KcC: ordered compaction emit (index-ascending -> deterministic). PARALLEL.
// ---------------------------------------------------------------------------
__global__ __launch_bounds__(1024) void kc_emit(const unsigned char* __restrict__ flag,
                                                const int* __restrict__ offs,
                                                int* __restrict__ rowlist) {
    __shared__ int wsum[16];
    __shared__ int woff[16];
    const int i = blockIdx.x * 1024 + threadIdx.x;
    const int pred = flag[i] ? 1 : 0;
    unsigned long long b = __ballot(pred);
    const int lane = threadIdx.x & 63, w = threadIdx.x >> 6;
    const int lanepre = __popcll(b & ((1ULL << lane) - 1ULL));
    if (lane == 0) wsum[w] = __popcll(b);
    __syncthreads();
    if (threadIdx.x == 0) {
        int s = 0;
        for (int k = 0; k < 16; ++k) { woff[k] = s; s += wsum[k]; }
    }
    __syncthreads();
    if (pred) rowlist[offs[blockIdx.x] + woff[w] + lanepre] = i;
}

// ---------------------------------------------------------------------------
// K0: pack Wn0|Ws0 (each 100x256 f32 [k][n]) into split-bf16 B fragments.
// ---------------------------------------------------------------------------
__global__ __launch_bounds__(256) void k0_packW(const float* __restrict__ Wn0,
                                                const float* __restrict__ Ws0,
                                                ushort* __restrict__ Wpk) {
    const int nb = blockIdx.x;           // 0..15
    for (int it = 0; it < 4; ++it) {
        const int task = threadIdx.x + it * 256;   // ks(8) x part(2) x lane(64)
        const int ks   = task >> 7;
        const int part = (task >> 6) & 1;
        const int lane = task & 63;
        const int n  = nb * 16 + (lane & 15);
        const int kb = (ks & 3) * 32 + (lane >> 4) * 8;
        const float* src = (ks < 4) ? Wn0 : Ws0;
        ushort out[8];
#pragma unroll
        for (int j = 0; j < 8; ++j) {
            const int k = kb + j;
            float v = (k < D_) ? src[k * H_ + n] : 0.f;
            ushort hi, lo;
            split_bf16(v, hi, lo);
            out[j] = part ? lo : hi;
        }
        ushort* dst = Wpk + ((size_t)((nb * 8 + ks) * 2 + part) * 64 + lane) * 8;
        *reinterpret_cast<bf8_t*>(dst) = *reinterpret_cast<bf8_t*>(out);
    }
}

// ---------------------------------------------------------------------------
// K12: fused gather-mean + pack + split-bf16 MFMA + bias + relu over the
// COMPACTED needed-row list. Shared 64KB LDS A-tile, nb-partitioned B across
// 4 waves; h (bf16) stores scatter to original rows.
// ---------------------------------------------------------------------------
__global__ __launch_bounds__(256) void k12_fused(const float* __restrict__ xf,
                                                 const int* __restrict__ col0,
                                                 const ushort* __restrict__ Wpk,
                                                 const float* __restrict__ b0,
                                                 const int* __restrict__ rowlist,
                                                 const int* __restrict__ ntot,
                                                 ushort* __restrict__ hb) {
    __shared__ ushort Afr[4][8][2][512];   // [rb][ks][part][lane*8+j] = 64 KB
    __shared__ int rl[64];
    const int n = ntot[0];
    if (blockIdx.x * 64 >= n) return;      // uniform early-exit, before barriers

    const int lane = threadIdx.x & 63;
    const int wid  = threadIdx.x >> 6;
    const int r    = lane & 15;
    const int kg   = lane >> 4;
    const int cidx = blockIdx.x * 64 + wid * 16 + r;   // compact index
    const bool act = (cidx < n);
    const int orow = rowlist[act ? cidx : 0];

    if (threadIdx.x < 64) {
        const int c2 = blockIdx.x * 64 + threadIdx.x;
        rl[threadIdx.x] = (c2 < n) ? rowlist[c2] : -1;
    }

    // ---- gather phase ----
    float accN[4][8];
    float accS[4][8];
#pragma unroll
    for (int ks = 0; ks < 4; ++ks)
#pragma unroll
        for (int j = 0; j < 8; ++j) { accN[ks][j] = 0.f; accS[ks][j] = 0.f; }

    if (act) {
        const int* cp = col0 + (size_t)orow * F0_;
        int idxs[F0_];
#pragma unroll
        for (int j = 0; j < F0_; ++j) idxs[j] = cp[j];   // break idx->row dep chain
#pragma unroll 5
        for (int jn = 0; jn < F0_; ++jn) {
            const float* rp = xf + (size_t)idxs[jn] * D_;
#pragma unroll
            for (int ks = 0; ks < 3; ++ks) {
                float4 a = *reinterpret_cast<const float4*>(rp + ks * 32 + kg * 8);
                float4 b = *reinterpret_cast<const float4*>(rp + ks * 32 + kg * 8 + 4);
                accN[ks][0] += a.x; accN[ks][1] += a.y; accN[ks][2] += a.z; accN[ks][3] += a.w;
                accN[ks][4] += b.x; accN[ks][5] += b.y; accN[ks][6] += b.z; accN[ks][7] += b.w;
            }
            if (kg == 0) {   // k = 96..99 only
                float4 a = *reinterpret_cast<const float4*>(rp + 96);
                accN[3][0] += a.x; accN[3][1] += a.y; accN[3][2] += a.z; accN[3][3] += a.w;
            }
        }
        const float* rp = xf + (size_t)orow * D_;
#pragma unroll
        for (int ks = 0; ks < 3; ++ks) {
            float4 a = *reinterpret_cast<const float4*>(rp + ks * 32 + kg * 8);
            float4 b = *reinterpret_cast<const float4*>(rp + ks * 32 + kg * 8 + 4);
            accS[ks][0] = a.x; accS[ks][1] = a.y; accS[ks][2] = a.z; accS[ks][3] = a.w;
            accS[ks][4] = b.x; accS[ks][5] = b.y; accS[ks][6] = b.z; accS[ks][7] = b.w;
        }
        if (kg == 0) {
            float4 a = *reinterpret_cast<const float4*>(rp + 96);
            accS[3][0] = a.x; accS[3][1] = a.y; accS[3][2] = a.z; accS[3][3] = a.w;
        }
    }

    // ---- pack phase: split-bf16 -> LDS fragments ----
    const float inv = 1.0f / F0_;
#pragma unroll
    for (int ks = 0; ks < 4; ++ks) {
        bf8_t hN, lN, hS, lS;
#pragma unroll
        for (int j = 0; j < 8; ++j) {
            ushort hi, lo;
            split_bf16(accN[ks][j] * inv, hi, lo);
            hN[j] = (short)hi; lN[j] = (short)lo;
            split_bf16(accS[ks][j], hi, lo);
            hS[j] = (short)hi; lS[j] = (short)lo;
        }
        *reinterpret_cast<bf8_t*>(&Afr[wid][ks    ][0][lane * 8]) = hN;
        *reinterpret_cast<bf8_t*>(&Afr[wid][ks    ][1][lane * 8]) = lN;
        *reinterpret_cast<bf8_t*>(&Afr[wid][ks + 4][0][lane * 8]) = hS;
        *reinterpret_cast<bf8_t*>(&Afr[wid][ks + 4][1][lane * 8]) = lS;
    }
    __syncthreads();

    // ---- MFMA phase: wave w -> cols [w*64, w*64+64) for all 64 block rows ----
    const int nb0 = wid * 4;
    f4_t acc[4][4] = {};
#pragma unroll
    for (int ks = 0; ks < 8; ++ks) {
        bf8_t ah[4], al[4], bh[4], bl[4];
#pragma unroll
        for (int rb = 0; rb < 4; ++rb) {
            ah[rb] = *reinterpret_cast<const bf8_t*>(&Afr[rb][ks][0][lane * 8]);
            al[rb] = *reinterpret_cast<const bf8_t*>(&Afr[rb][ks][1][lane * 8]);
        }
#pragma unroll
        for (int ci = 0; ci < 4; ++ci) {
            const ushort* p = Wpk + ((size_t)(((nb0 + ci) * 8 + ks) * 2) * 64 + lane) * 8;
            bh[ci] = *reinterpret_cast<const bf8_t*>(p);
            bl[ci] = *reinterpret_cast<const bf8_t*>(p + 512);
        }
#pragma unroll
        for (int rb = 0; rb < 4; ++rb)
#pragma unroll
            for (int ci = 0; ci < 4; ++ci) {
                acc[rb][ci] = __builtin_amdgcn_mfma_f32_16x16x32_bf16(ah[rb], bh[ci], acc[rb][ci], 0, 0, 0);
                acc[rb][ci] = __builtin_amdgcn_mfma_f32_16x16x32_bf16(ah[rb], bl[ci], acc[rb][ci], 0, 0, 0);
                acc[rb][ci] = __builtin_amdgcn_mfma_f32_16x16x32_bf16(al[rb], bh[ci], acc[rb][ci], 0, 0, 0);
            }
    }

    // ---- epilogue: bias + relu + bf16 scatter-store to original rows ----
    const int col_in = lane & 15;
    const int rgrp   = lane >> 4;
    int orows[4][4];
#pragma unroll
    for (int rb = 0; rb < 4; ++rb)
#pragma unroll
        for (int q = 0; q < 4; ++q)
            orows[rb][q] = rl[rb * 16 + rgrp * 4 + q];
#pragma unroll
    for (int ci = 0; ci < 4; ++ci) {
        const int nn = (nb0 + ci) * 16 + col_in;
        const float bias = b0[nn];
#pragma unroll
        for (int rb = 0; rb < 4; ++rb) {
#pragma unroll
            for (int q = 0; q < 4; ++q) {
                const int o = orows[rb][q];
                if (o >= 0) {
                    float v = acc[rb][ci][q] + bias;
                    v = v > 0.f ? v : 0.f;
                    __hip_bfloat16 bv = __float2bfloat16(v);
                    hb[(size_t)o * H_ + nn] = *reinterpret_cast<ushort*>(&bv);
                }
            }
        }
    }
}

// ---------------------------------------------------------------------------
// K3: out_u = (mean_j h[col1]) @ Wn1 + h[:T1] @ Ws1 + b1   (T1 x 128)
// h is bf16; accumulate f32.
// ---------------------------------------------------------------------------
__global__ __launch_bounds__(256) void k3_layer1(const ushort* __restrict__ hb,
                                                 const int* __restrict__ col1,
                                                 const float* __restrict__ Wn1,
                                                 const float* __restrict__ Ws1,
                                                 const float* __restrict__ b1,
                                                 float* __restrict__ out_u) {
    __shared__ __align__(16) float Ng[16 * H_];
    __shared__ __align__(16) float Sf[16 * H_];
    const int t = threadIdx.x;
    const int base = blockIdx.x * 16;

    for (int r = 0; r < 16; ++r) {
        float a = 0.f;
#pragma unroll
        for (int j = 0; j < F1_; ++j) {
            int idx = col1[(base + r) * F1_ + j];
            a += bf2f(hb[(size_t)idx * H_ + t]);
        }
        Ng[r * H_ + t] = a * (1.0f / F1_);
        Sf[r * H_ + t] = bf2f(hb[(size_t)(base + r) * H_ + t]);
    }
    __syncthreads();

    const int c  = t & (C_ - 1);
    const int rg = t >> 7;
    float acc[8];
    const float bias = b1[c];
#pragma unroll
    for (int r8 = 0; r8 < 8; ++r8) acc[r8] = bias;

    for (int d4 = 0; d4 < H_ / 4; ++d4) {
        const int d = d4 * 4;
        const float wn0_ = Wn1[(d + 0) * C_ + c];
        const float wn1_ = Wn1[(d + 1) * C_ + c];
        const float wn2_ = Wn1[(d + 2) * C_ + c];
        const float wn3_ = Wn1[(d + 3) * C_ + c];
        const float ws0_ = Ws1[(d + 0) * C_ + c];
        const float ws1_ = Ws1[(d + 1) * C_ + c];
        const float ws2_ = Ws1[(d + 2) * C_ + c];
        const float ws3_ = Ws1[(d + 3) * C_ + c];
#pragma unroll
        for (int r8 = 0; r8 < 8; ++r8) {
            const int r = rg * 8 + r8;
            float4 n = *reinterpret_cast<const float4*>(&Ng[r * H_ + d]);
            float4 s = *reinterpret_cast<const float4*>(&Sf[r * H_ + d]);
            acc[r8] += n.x * wn0_ + n.y * wn1_ + n.z * wn2_ + n.w * wn3_
                     + s.x * ws0_ + s.y * ws1_ + s.z * ws2_ + s.w * ws3_;
        }
    }
#pragma unroll
    for (int r8 = 0; r8 < 8; ++r8)
        out_u[(size_t)(base + rg * 8 + r8) * C_ + c] = acc[r8];
}

// ---------------------------------------------------------------------------
// K4: edge scores (8192 edges)
// ---------------------------------------------------------------------------
__global__ __launch_bounds__(256) void k4_edges(const float* __restrict__ out_u,
                                                const int* __restrict__ rmap,
                                                const float* __restrict__ Wp1,
                                                const float* __restrict__ bp1,
                                                const float* __restrict__ Wp2,
                                                const float* __restrict__ bp2,
                                                float* __restrict__ scores) {
    __shared__ __align__(16) float E[32 * C_];
    const int t = threadIdx.x;
    const int base = blockIdx.x * 32;
    const int f = t & 127;
    const int half = t >> 7;

    for (int rr = 0; rr < 16; ++rr) {
        const int row = rr * 2 + half;
        const int j = base + row;
        const int si = rmap[j & (IC_ - 1)];
        const int di = rmap[IC_ + j];
        E[row * C_ + f] = out_u[(size_t)si * C_ + f] * out_u[(size_t)di * C_ + f];
    }
    __syncthreads();

    float acc[16];
    const float bias = bp1[f];
#pragma unroll
    for (int r16 = 0; r16 < 16; ++r16) acc[r16] = bias;

    for (int d4 = 0; d4 < C_ / 4; ++d4) {
        const int d = d4 * 4;
        const float w0 = Wp1[(d + 0) * C_ + f];
        const float w1 = Wp1[(d + 1) * C_ + f];
        const float w2 = Wp1[(d + 2) * C_ + f];
        const float w3 = Wp1[(d + 3) * C_ + f];
#pragma unroll
        for (int r16 = 0; r16 < 16; ++r16) {
            const int r = half * 16 + r16;
            float4 e4 = *reinterpret_cast<const float4*>(&E[r * C_ + d]);
            acc[r16] += e4.x * w0 + e4.y * w1 + e4.z * w2 + e4.w * w3;
        }
    }
    __syncthreads();
#pragma unroll
    for (int r16 = 0; r16 < 16; ++r16) {
        float v = acc[r16];
        E[(half * 16 + r16) * C_ + f] = v > 0.f ? v : 0.f;
    }
    __syncthreads();

    const int r = t >> 3;
    const int s = t & 7;
    float p = 0.f;
#pragma unroll
    for (int k4 = 0; k4 < 4; ++k4) {
        float4 tv = *reinterpret_cast<const float4*>(&E[r * C_ + s * 16 + k4 * 4]);
        float4 wv = *reinterpret_cast<const float4*>(&Wp2[s * 16 + k4 * 4]);
        p += tv.x * wv.x + tv.y * wv.y + tv.z * wv.z + tv.w * wv.w;
    }
    p += __shfl_down(p, 4, 8);
    p += __shfl_down(p, 2, 8);
    p += __shfl_down(p, 1, 8);
    if (s == 0) scores[base + r] = p + bp2[0];
}

// ---------------------------------------------------------------------------
extern "C" void kernel_launch(void* const* d_in, const int* in_sizes, int n_in,
                              void* d_out, int out_size, void* d_ws, size_t ws_size,
                              hipStream_t stream) {
    const float* xf   = (const float*)d_in[0];
    const float* Wn0  = (const float*)d_in[1];
    const float* Ws0  = (const float*)d_in[2];
    const float* b0   = (const float*)d_in[3];
    const float* Wn1  = (const float*)d_in[4];
    const float* Ws1  = (const float*)d_in[5];
    const float* b1   = (const float*)d_in[6];
    const float* Wp1  = (const float*)d_in[7];
    const float* bp1  = (const float*)d_in[8];
    const float* Wp2  = (const float*)d_in[9];
    const float* bp2  = (const float*)d_in[10];
    const int*   col0 = (const int*)d_in[11];
    const int*   col1 = (const int*)d_in[12];
    const int*   rmap = (const int*)d_in[13];

    // workspace layout
    char* ws = (char*)d_ws;
    ushort* hb    = (ushort*)ws;                                // T0*256 bf16 = 69.2 MB
    float*  out_u = (float*)(ws + (size_t)T0_ * H_ * 2);        // T1*128 f32 = 6.3 MB
    ushort* Wpk   = (ushort*)(out_u + (size_t)T1_ * C_);        // 512 KB
    unsigned char* flag = (unsigned char*)(Wpk + (size_t)16 * 8 * 2 * 64 * 8); // T0 B
    int*    counts  = (int*)(flag + T0_);                       // 132
    int*    offs    = counts + CBLK_;                           // 132
    int*    ntot    = offs + CBLK_;                             // 1
    int*    rowlist = ntot + 1;                                 // T0
    float*  scores  = (float*)d_out;

    hipLaunchKernelGGL(bz_zero, dim3((T0_ / 4 + 255) / 256), dim3(256), 0, stream,
                       (unsigned int*)flag);
    hipLaunchKernelGGL(bs_set, dim3((T1_ * F1_ + 255) / 256), dim3(256), 0, stream,
                       col1, flag);
    hipLaunchKernelGGL(kc_count, dim3(CBLK_), dim3(1024), 0, stream, flag, counts);
    hipLaunchKernelGGL(kc_scan, dim3(1), dim3(64), 0, stream, counts, offs, ntot);
    hipLaunchKernelGGL(kc_emit, dim3(CBLK_), dim3(1024), 0, stream, flag, offs, rowlist);
    hipLaunchKernelGGL(k0_packW, dim3(16), dim3(256), 0, stream, Wn0, Ws0, Wpk);
    hipLaunchKernelGGL(k12_fused, dim3(T0_ / 64), dim3(256), 0, stream,
                       xf, col0, Wpk, b0, rowlist, ntot, hb);
    hipLaunchKernelGGL(k3_layer1, dim3(T1_ / 16), dim3(256), 0, stream,
                       hb, col1, Wn1, Ws1, b1, out_u);
    hipLaunchKernelGGL(k4_edges, dim3((2 * IC_) / 32), dim3(256), 0, stream,
                       out_u, rmap, Wp1, bp1, Wp2, bp2, scores);
}